// Round 3
// baseline (664.282 us; speedup 1.0000x reference)
//
#include <hip/hip_runtime.h>
#include <math.h>

#define H     2048
#define NE    64
#define TOKB  64              // tokens per block = lanes per wave
#define NWAVE 8
#define KSPL  (H / NWAVE)     // 256 K per wave
#define RST   68              // padded LDS row stride (floats)
#define TAU   4.0e-3f         // fp32-vs-ref rank-safety margin (~400x noise)
#define NEGF  (-3.0e38f)

// ---- Pass 1: lane=token, W scalar-loaded (SGPR), acc[64] in VGPRs ---------
__global__ __launch_bounds__(512, 2) void moe_gate_main(
    const float* __restrict__ x,   // [T, H]
    const float* __restrict__ w,   // [NE, H]
    float* __restrict__ out,       // [2T idx][2T weights]
    int woff,
    unsigned char* __restrict__ flags)  // [T]
{
    __shared__ float red[2][TOKB][RST];   // 34816 B, reduction only

    const int lane = threadIdx.x & 63;
    const int wv   = threadIdx.x >> 6;    // 0..7
    const int t    = blockIdx.x * TOKB + lane;
    const int k0   = wv * KSPL;

    float acc[NE];
#pragma unroll
    for (int e = 0; e < NE; ++e) acc[e] = 0.f;

    const float* xrow = x + (size_t)t * H + k0;

    for (int c = 0; c < KSPL; c += 32) {
        // per-lane x: one full 128B line, single touch
        const float4 xq0 = *reinterpret_cast<const float4*>(&xrow[c +  0]);
        const float4 xq1 = *reinterpret_cast<const float4*>(&xrow[c +  4]);
        const float4 xq2 = *reinterpret_cast<const float4*>(&xrow[c +  8]);
        const float4 xq3 = *reinterpret_cast<const float4*>(&xrow[c + 12]);
        const float4 xq4 = *reinterpret_cast<const float4*>(&xrow[c + 16]);
        const float4 xq5 = *reinterpret_cast<const float4*>(&xrow[c + 20]);
        const float4 xq6 = *reinterpret_cast<const float4*>(&xrow[c + 24]);
        const float4 xq7 = *reinterpret_cast<const float4*>(&xrow[c + 28]);

#pragma unroll
        for (int e = 0; e < NE; ++e) {     // full unroll: acc[] static-indexed
            const float* wr = &w[(size_t)e * H + k0 + c];  // wave-uniform addr
            const float4 a0 = *reinterpret_cast<const float4*>(wr +  0);
            const float4 a1 = *reinterpret_cast<const float4*>(wr +  4);
            const float4 a2 = *reinterpret_cast<const float4*>(wr +  8);
            const float4 a3 = *reinterpret_cast<const float4*>(wr + 12);
            const float4 a4 = *reinterpret_cast<const float4*>(wr + 16);
            const float4 a5 = *reinterpret_cast<const float4*>(wr + 20);
            const float4 a6 = *reinterpret_cast<const float4*>(wr + 24);
            const float4 a7 = *reinterpret_cast<const float4*>(wr + 28);
            float s = acc[e];
            s = fmaf(a0.x, xq0.x, s); s = fmaf(a0.y, xq0.y, s);
            s = fmaf(a0.z, xq0.z, s); s = fmaf(a0.w, xq0.w, s);
            s = fmaf(a1.x, xq1.x, s); s = fmaf(a1.y, xq1.y, s);
            s = fmaf(a1.z, xq1.z, s); s = fmaf(a1.w, xq1.w, s);
            s = fmaf(a2.x, xq2.x, s); s = fmaf(a2.y, xq2.y, s);
            s = fmaf(a2.z, xq2.z, s); s = fmaf(a2.w, xq2.w, s);
            s = fmaf(a3.x, xq3.x, s); s = fmaf(a3.y, xq3.y, s);
            s = fmaf(a3.z, xq3.z, s); s = fmaf(a3.w, xq3.w, s);
            s = fmaf(a4.x, xq4.x, s); s = fmaf(a4.y, xq4.y, s);
            s = fmaf(a4.z, xq4.z, s); s = fmaf(a4.w, xq4.w, s);
            s = fmaf(a5.x, xq5.x, s); s = fmaf(a5.y, xq5.y, s);
            s = fmaf(a5.z, xq5.z, s); s = fmaf(a5.w, xq5.w, s);
            s = fmaf(a6.x, xq6.x, s); s = fmaf(a6.y, xq6.y, s);
            s = fmaf(a6.z, xq6.z, s); s = fmaf(a6.w, xq6.w, s);
            s = fmaf(a7.x, xq7.x, s); s = fmaf(a7.y, xq7.y, s);
            s = fmaf(a7.z, xq7.z, s); s = fmaf(a7.w, xq7.w, s);
            acc[e] = s;
        }
    }

    // ---- 8-wave K-split tree reduction via LDS (2 buffers) ----
    // A: {4,5}->buf{0,1}, {0,1} add.  B: {6,7}->buf{0,1}, {2,3} add.
    // C: {2,3}->buf{0,1}, {0,1} add.  D: {1}->buf0, {0} adds.
    if (wv == 4 || wv == 5) {
#pragma unroll
        for (int e = 0; e < NE; e += 4)
            *reinterpret_cast<float4*>(&red[wv - 4][lane][e]) =
                make_float4(acc[e], acc[e+1], acc[e+2], acc[e+3]);
    }
    __syncthreads();
    if (wv < 2) {
#pragma unroll
        for (int e = 0; e < NE; ++e) acc[e] += red[wv][lane][e];
    }
    __syncthreads();
    if (wv == 6 || wv == 7) {
#pragma unroll
        for (int e = 0; e < NE; e += 4)
            *reinterpret_cast<float4*>(&red[wv - 6][lane][e]) =
                make_float4(acc[e], acc[e+1], acc[e+2], acc[e+3]);
    }
    __syncthreads();
    if (wv == 2 || wv == 3) {
#pragma unroll
        for (int e = 0; e < NE; ++e) acc[e] += red[wv - 2][lane][e];
    }
    __syncthreads();
    if (wv == 2 || wv == 3) {
#pragma unroll
        for (int e = 0; e < NE; e += 4)
            *reinterpret_cast<float4*>(&red[wv - 2][lane][e]) =
                make_float4(acc[e], acc[e+1], acc[e+2], acc[e+3]);
    }
    __syncthreads();
    if (wv < 2) {
#pragma unroll
        for (int e = 0; e < NE; ++e) acc[e] += red[wv][lane][e];
    }
    __syncthreads();
    if (wv == 1) {
#pragma unroll
        for (int e = 0; e < NE; e += 4)
            *reinterpret_cast<float4*>(&red[0][lane][e]) =
                make_float4(acc[e], acc[e+1], acc[e+2], acc[e+3]);
    }
    __syncthreads();

    if (wv == 0) {
#pragma unroll
        for (int e = 0; e < NE; ++e) acc[e] += red[0][lane][e];

        // in-lane stable top-3 (strict > keeps lowest index on ties)
        float m1 = NEGF, m2 = NEGF, m3 = NEGF;
        int   i1 = 0, i2 = 0;
#pragma unroll
        for (int e = 0; e < NE; ++e) {
            const float v = acc[e];
            if (v > m1)      { m3 = m2; m2 = m1; i2 = i1; m1 = v; i1 = e; }
            else if (v > m2) { m3 = m2; m2 = v; i2 = e; }
            else if (v > m3) { m3 = v; }
        }

        const float r = expf(m2 - m1);     // <= 1
        const float s = 1.0f + r;
        out[2 * t + 0]        = (float)i1;
        out[2 * t + 1]        = (float)i2;
        out[woff + 2 * t + 0] = 1.0f / s;
        out[woff + 2 * t + 1] = r / s;
        flags[t] = ((m1 - m2 < TAU) || (m2 - m3 < TAU)) ? 1 : 0;
    }
}

// ---- Pass 2: fp64 refine; wave-parallel ballot scan of flags --------------
__global__ __launch_bounds__(256) void moe_refine_fp64(
    const float* __restrict__ x, const float* __restrict__ w,
    float* __restrict__ out, int woff,
    const unsigned char* __restrict__ flags, int nstripe)
{
    const int lane   = threadIdx.x & 63;
    const int wv     = threadIdx.x >> 6;
    const int stripe = blockIdx.x * 4 + wv;   // one 64-token stripe per wave
    if (stripe >= nstripe) return;

    unsigned long long m = __ballot(flags[stripe * 64 + lane] != 0);

    while (m) {
        const int t = stripe * 64 + (int)__builtin_ctzll(m);
        m &= m - 1;

        double a0 = 0.0, a1 = 0.0, a2 = 0.0, a3 = 0.0;
        const float* wr = &w[(size_t)lane * H];   // lane = expert
        const float* xr = &x[(size_t)t * H];
        for (int k = 0; k < H; k += 16) {
            const float4 wq0 = *reinterpret_cast<const float4*>(&wr[k +  0]);
            const float4 wq1 = *reinterpret_cast<const float4*>(&wr[k +  4]);
            const float4 wq2 = *reinterpret_cast<const float4*>(&wr[k +  8]);
            const float4 wq3 = *reinterpret_cast<const float4*>(&wr[k + 12]);
            const float4 xq0 = *reinterpret_cast<const float4*>(&xr[k +  0]);
            const float4 xq1 = *reinterpret_cast<const float4*>(&xr[k +  4]);
            const float4 xq2 = *reinterpret_cast<const float4*>(&xr[k +  8]);
            const float4 xq3 = *reinterpret_cast<const float4*>(&xr[k + 12]);
            a0 = fma((double)wq0.x, (double)xq0.x, a0);
            a0 = fma((double)wq0.y, (double)xq0.y, a0);
            a0 = fma((double)wq0.z, (double)xq0.z, a0);
            a0 = fma((double)wq0.w, (double)xq0.w, a0);
            a1 = fma((double)wq1.x, (double)xq1.x, a1);
            a1 = fma((double)wq1.y, (double)xq1.y, a1);
            a1 = fma((double)wq1.z, (double)xq1.z, a1);
            a1 = fma((double)wq1.w, (double)xq1.w, a1);
            a2 = fma((double)wq2.x, (double)xq2.x, a2);
            a2 = fma((double)wq2.y, (double)xq2.y, a2);
            a2 = fma((double)wq2.z, (double)xq2.z, a2);
            a2 = fma((double)wq2.w, (double)xq2.w, a2);
            a3 = fma((double)wq3.x, (double)xq3.x, a3);
            a3 = fma((double)wq3.y, (double)xq3.y, a3);
            a3 = fma((double)wq3.z, (double)xq3.z, a3);
            a3 = fma((double)wq3.w, (double)xq3.w, a3);
        }
        const double acc = (a0 + a1) + (a2 + a3);

        double v = acc; int bi = lane;
#pragma unroll
        for (int off = 32; off > 0; off >>= 1) {
            double ov = __shfl_xor(v, off);
            int    oi = __shfl_xor(bi, off);
            if (ov > v || (ov == v && oi < bi)) { v = ov; bi = oi; }
        }
        const double m1 = v; const int i1 = bi;

        double v2 = (lane == i1) ? -1.0e300 : acc; int b2 = lane;
#pragma unroll
        for (int off = 32; off > 0; off >>= 1) {
            double ov = __shfl_xor(v2, off);
            int    oi = __shfl_xor(b2, off);
            if (ov > v2 || (ov == v2 && oi < b2)) { v2 = ov; b2 = oi; }
        }
        const double m2 = v2; const int i2 = b2;

        if (lane == 0) {
            const double r = exp(m2 - m1);
            const double s = 1.0 + r;
            out[2 * t + 0]        = (float)i1;
            out[2 * t + 1]        = (float)i2;
            out[woff + 2 * t + 0] = (float)(1.0 / s);
            out[woff + 2 * t + 1] = (float)(r / s);
        }
    }
}

extern "C" void kernel_launch(void* const* d_in, const int* in_sizes, int n_in,
                              void* d_out, int out_size, void* d_ws, size_t ws_size,
                              hipStream_t stream) {
    const float* x   = (const float*)d_in[0];
    const float* wgt = (const float*)d_in[1];
    float* out = (float*)d_out;

    const int T    = in_sizes[0] / H;   // 16384
    const int woff = out_size / 2;      // 32768
    unsigned char* flags = (unsigned char*)d_ws;  // [T], fully rewritten per call

    moe_gate_main<<<dim3(T / TOKB), dim3(512), 0, stream>>>(
        x, wgt, out, woff, flags);

    const int nstripe = T / 64;         // 256
    moe_refine_fp64<<<dim3((nstripe + 3) / 4), dim3(256), 0, stream>>>(
        x, wgt, out, woff, flags, nstripe);
}

// Round 4
// 307.368 us; speedup vs baseline: 2.1612x; 2.1612x over previous
//
#include <hip/hip_runtime.h>
#include <math.h>

#define H      2048
#define NE     64
#define TOKB   16            // tokens per block
#define KCHUNK 128           // K per staged chunk (4 waves x 32)
#define KW     32            // K window per wave per chunk
#define NCH    (H / KCHUNK)  // 16 chunks
#define WST    132           // LDS row stride (floats): 16B-aligned, bank-spread
#define SCST   68            // score row stride (floats)
#define XOFF   8448          // Ws = 64 rows * 132
#define TAU    4.0e-3f
#define NEGF   (-3.0e38f)

// ---------------- Pass 1: 4x4 register-tiled fp32, K-split across waves ----
__global__ __launch_bounds__(256) void moe_gate_main(
    const float* __restrict__ x,   // [T, H]
    const float* __restrict__ w,   // [NE, H]
    float* __restrict__ out,       // [2T idx][2T weights]
    int woff,
    unsigned char* __restrict__ flags)
{
    __shared__ float lds[XOFF + TOKB * WST];   // 42240 B; reused for reduction
    float* Ws = lds;                           // [64][WST], row-permuted
    float* Xs = lds + XOFF;                    // [16][WST], row-permuted

    const int tid  = threadIdx.x;
    const int lane = tid & 63;
    const int wv   = tid >> 6;        // 0..3 : K-split index
    const int eg   = lane & 15;       // expert group: experts eg*4 .. +3
    const int tg   = lane >> 4;       // token group: tokens tg*4 .. +3
    const int t0   = blockIdx.x * TOKB;

    // staging maps (q = j*256 + tid over float4s; 32 f4 per row)
    const int r8   = tid >> 5;              // 0..7
    const int colW = (tid & 31) * 4;        // float col 0..124
    // X rows: t in [0,16): thread stages t = r8 and t = 8 + r8
    const int xdst0 = ((r8 & 3) * 4 + (r8 >> 2)) * WST + colW;
    const int xdst1 = (((8 + r8) & 3) * 4 + ((8 + r8) >> 2)) * WST + colW;

    float4 wbuf[8], xbuf[2];

    // prologue: load chunk 0
    {
        #pragma unroll
        for (int j = 0; j < 8; ++j) {
            const int e = j * 8 + r8;
            wbuf[j] = *reinterpret_cast<const float4*>(&w[(size_t)e * H + colW]);
        }
        xbuf[0] = *reinterpret_cast<const float4*>(&x[(size_t)(t0 + r8) * H + colW]);
        xbuf[1] = *reinterpret_cast<const float4*>(&x[(size_t)(t0 + 8 + r8) * H + colW]);
    }

    float acc[4][4];
    #pragma unroll
    for (int i = 0; i < 4; ++i)
        #pragma unroll
        for (int j = 0; j < 4; ++j) acc[i][j] = 0.f;

    for (int c = 0; c < NCH; ++c) {
        __syncthreads();                       // LDS free (prev compute done)
        #pragma unroll
        for (int j = 0; j < 8; ++j) {
            const int e = j * 8 + r8;
            const int wdst = ((e & 3) * 16 + (e >> 2)) * WST + colW;
            *reinterpret_cast<float4*>(&Ws[wdst]) = wbuf[j];
        }
        *reinterpret_cast<float4*>(&Xs[xdst0]) = xbuf[0];
        *reinterpret_cast<float4*>(&Xs[xdst1]) = xbuf[1];
        __syncthreads();

        if (c + 1 < NCH) {                     // prefetch next chunk
            const size_t k0 = (size_t)(c + 1) * KCHUNK;
            #pragma unroll
            for (int j = 0; j < 8; ++j) {
                const int e = j * 8 + r8;
                wbuf[j] = *reinterpret_cast<const float4*>(&w[(size_t)e * H + k0 + colW]);
            }
            xbuf[0] = *reinterpret_cast<const float4*>(&x[(size_t)(t0 + r8) * H + k0 + colW]);
            xbuf[1] = *reinterpret_cast<const float4*>(&x[(size_t)(t0 + 8 + r8) * H + k0 + colW]);
        }

        const int base = wv * KW;
        #pragma unroll
        for (int kq = 0; kq < 8; ++kq) {
            const int col = base + kq * 4;
            // X: rows r = j*4 + tg (t = tg*4 + j); lanes vary tg -> 4 banks apart
            const float4 xq0 = *reinterpret_cast<const float4*>(&Xs[(0 * 4 + tg) * WST + col]);
            const float4 xq1 = *reinterpret_cast<const float4*>(&Xs[(1 * 4 + tg) * WST + col]);
            const float4 xq2 = *reinterpret_cast<const float4*>(&Xs[(2 * 4 + tg) * WST + col]);
            const float4 xq3 = *reinterpret_cast<const float4*>(&Xs[(3 * 4 + tg) * WST + col]);
            // W: rows r = i*16 + eg (e = eg*4 + i); lanes vary eg -> 2-way max
            const float4 wq0 = *reinterpret_cast<const float4*>(&Ws[(0 * 16 + eg) * WST + col]);
            const float4 wq1 = *reinterpret_cast<const float4*>(&Ws[(1 * 16 + eg) * WST + col]);
            const float4 wq2 = *reinterpret_cast<const float4*>(&Ws[(2 * 16 + eg) * WST + col]);
            const float4 wq3 = *reinterpret_cast<const float4*>(&Ws[(3 * 16 + eg) * WST + col]);

#define DOT4(i, j, WQ, XQ)                                   \
            acc[i][j] = fmaf(WQ.x, XQ.x, acc[i][j]);         \
            acc[i][j] = fmaf(WQ.y, XQ.y, acc[i][j]);         \
            acc[i][j] = fmaf(WQ.z, XQ.z, acc[i][j]);         \
            acc[i][j] = fmaf(WQ.w, XQ.w, acc[i][j]);

            DOT4(0, 0, wq0, xq0) DOT4(0, 1, wq0, xq1) DOT4(0, 2, wq0, xq2) DOT4(0, 3, wq0, xq3)
            DOT4(1, 0, wq1, xq0) DOT4(1, 1, wq1, xq1) DOT4(1, 2, wq1, xq2) DOT4(1, 3, wq1, xq3)
            DOT4(2, 0, wq2, xq0) DOT4(2, 1, wq2, xq1) DOT4(2, 2, wq2, xq2) DOT4(2, 3, wq2, xq3)
            DOT4(3, 0, wq3, xq0) DOT4(3, 1, wq3, xq1) DOT4(3, 2, wq3, xq2) DOT4(3, 3, wq3, xq3)
#undef DOT4
        }
    }

    // ---------------- K-split reduction via LDS (reuse lds) ----------------
    __syncthreads();                           // done reading Ws/Xs
    float* S = lds;                            // 4 regions of [16][SCST]
    #pragma unroll
    for (int i = 0; i < 4; ++i)
        #pragma unroll
        for (int j = 0; j < 4; ++j)
            S[wv * (TOKB * SCST) + (tg * 4 + j) * SCST + (eg * 4 + i)] = acc[i][j];
    __syncthreads();
    {
        const int tok = tid >> 4;              // 0..15
        const int e4  = (tid & 15) * 4;        // 0..60
        const int off = tok * SCST + e4;
        const float4 s0 = *reinterpret_cast<const float4*>(&S[0 * (TOKB * SCST) + off]);
        const float4 s1 = *reinterpret_cast<const float4*>(&S[1 * (TOKB * SCST) + off]);
        const float4 s2 = *reinterpret_cast<const float4*>(&S[2 * (TOKB * SCST) + off]);
        const float4 s3 = *reinterpret_cast<const float4*>(&S[3 * (TOKB * SCST) + off]);
        float4 r;
        r.x = (s0.x + s1.x) + (s2.x + s3.x);
        r.y = (s0.y + s1.y) + (s2.y + s3.y);
        r.z = (s0.z + s1.z) + (s2.z + s3.z);
        r.w = (s0.w + s1.w) + (s2.w + s3.w);
        *reinterpret_cast<float4*>(&S[off]) = r;   // each cell read+written by same thread only
    }
    __syncthreads();

    // ---------------- top-3 scan (stable: strict >, ascending e) ------------
    if (tid < TOKB) {
        const float* row = &S[tid * SCST];
        float m1 = NEGF, m2 = NEGF, m3 = NEGF;
        int   i1 = 0, i2 = 0;
        #pragma unroll
        for (int e = 0; e < NE; ++e) {
            const float v = row[e];
            if (v > m1)      { m3 = m2; m2 = m1; i2 = i1; m1 = v; i1 = e; }
            else if (v > m2) { m3 = m2; m2 = v; i2 = e; }
            else if (v > m3) { m3 = v; }
        }
        const float r = expf(m2 - m1);         // <= 1
        const float s = 1.0f + r;
        const int   t = t0 + tid;
        out[2 * t + 0]        = (float)i1;
        out[2 * t + 1]        = (float)i2;
        out[woff + 2 * t + 0] = 1.0f / s;
        out[woff + 2 * t + 1] = r / s;
        flags[t] = ((m1 - m2 < TAU) || (m2 - m3 < TAU)) ? 1 : 0;
    }
}

// ---------------- Pass 2: fp64 refine, ONE WAVE PER TOKEN -------------------
__global__ __launch_bounds__(256) void moe_refine_fp64(
    const float* __restrict__ x, const float* __restrict__ w,
    float* __restrict__ out, int woff,
    const unsigned char* __restrict__ flags, int T)
{
    const int lane = threadIdx.x & 63;
    const int t    = blockIdx.x * 4 + (threadIdx.x >> 6);
    if (t >= T) return;
    if (flags[t] == 0) return;                 // wave-uniform early exit

    double a0 = 0.0, a1 = 0.0, a2 = 0.0, a3 = 0.0;
    const float* wr = &w[(size_t)lane * H];    // lane = expert
    const float* xr = &x[(size_t)t * H];
    for (int k = 0; k < H; k += 16) {
        const float4 wq0 = *reinterpret_cast<const float4*>(&wr[k +  0]);
        const float4 wq1 = *reinterpret_cast<const float4*>(&wr[k +  4]);
        const float4 wq2 = *reinterpret_cast<const float4*>(&wr[k +  8]);
        const float4 wq3 = *reinterpret_cast<const float4*>(&wr[k + 12]);
        const float4 xq0 = *reinterpret_cast<const float4*>(&xr[k +  0]);
        const float4 xq1 = *reinterpret_cast<const float4*>(&xr[k +  4]);
        const float4 xq2 = *reinterpret_cast<const float4*>(&xr[k +  8]);
        const float4 xq3 = *reinterpret_cast<const float4*>(&xr[k + 12]);
        a0 = fma((double)wq0.x, (double)xq0.x, a0);
        a0 = fma((double)wq0.y, (double)xq0.y, a0);
        a0 = fma((double)wq0.z, (double)xq0.z, a0);
        a0 = fma((double)wq0.w, (double)xq0.w, a0);
        a1 = fma((double)wq1.x, (double)xq1.x, a1);
        a1 = fma((double)wq1.y, (double)xq1.y, a1);
        a1 = fma((double)wq1.z, (double)xq1.z, a1);
        a1 = fma((double)wq1.w, (double)xq1.w, a1);
        a2 = fma((double)wq2.x, (double)xq2.x, a2);
        a2 = fma((double)wq2.y, (double)xq2.y, a2);
        a2 = fma((double)wq2.z, (double)xq2.z, a2);
        a2 = fma((double)wq2.w, (double)xq2.w, a2);
        a3 = fma((double)wq3.x, (double)xq3.x, a3);
        a3 = fma((double)wq3.y, (double)xq3.y, a3);
        a3 = fma((double)wq3.z, (double)xq3.z, a3);
        a3 = fma((double)wq3.w, (double)xq3.w, a3);
    }
    const double acc = (a0 + a1) + (a2 + a3);

    double v = acc; int bi = lane;
    #pragma unroll
    for (int off = 32; off > 0; off >>= 1) {
        double ov = __shfl_xor(v, off);
        int    oi = __shfl_xor(bi, off);
        if (ov > v || (ov == v && oi < bi)) { v = ov; bi = oi; }
    }
    const double m1 = v; const int i1 = bi;

    double v2 = (lane == i1) ? -1.0e300 : acc; int b2 = lane;
    #pragma unroll
    for (int off = 32; off > 0; off >>= 1) {
        double ov = __shfl_xor(v2, off);
        int    oi = __shfl_xor(b2, off);
        if (ov > v2 || (ov == v2 && oi < b2)) { v2 = ov; b2 = oi; }
    }
    const double m2 = v2; const int i2 = b2;

    if (lane == 0) {
        const double r = exp(m2 - m1);
        const double s = 1.0 + r;
        out[2 * t + 0]        = (float)i1;
        out[2 * t + 1]        = (float)i2;
        out[woff + 2 * t + 0] = (float)(1.0 / s);
        out[woff + 2 * t + 1] = (float)(r / s);
    }
}

extern "C" void kernel_launch(void* const* d_in, const int* in_sizes, int n_in,
                              void* d_out, int out_size, void* d_ws, size_t ws_size,
                              hipStream_t stream) {
    const float* x   = (const float*)d_in[0];
    const float* wgt = (const float*)d_in[1];
    float* out = (float*)d_out;

    const int T    = in_sizes[0] / H;   // 16384
    const int woff = out_size / 2;      // 32768
    unsigned char* flags = (unsigned char*)d_ws;  // [T], fully rewritten per call

    moe_gate_main<<<dim3(T / TOKB), dim3(256), 0, stream>>>(
        x, wgt, out, woff, flags);

    moe_refine_fp64<<<dim3(T / 4), dim3(256), 0, stream>>>(
        x, wgt, out, woff, flags, T);
}

// Round 5
// 101.864 us; speedup vs baseline: 6.5212x; 3.0174x over previous
//
#include <hip/hip_runtime.h>
#include <math.h>

#define H    2048
#define NE   64
#define TAU  4.0e-3f
#define NEGF (-3.0e38f)

typedef __bf16 bf16x8 __attribute__((ext_vector_type(8)));
typedef float  f32x16 __attribute__((ext_vector_type(16)));

// split a fp32 octet (2x float4, consecutive k) into bf16 hi + lo fragments
__device__ __forceinline__ void cvt8(const float4 a, const float4 b,
                                     bf16x8& hi, bf16x8& lo) {
    const float v0 = a.x, v1 = a.y, v2 = a.z, v3 = a.w;
    const float v4 = b.x, v5 = b.y, v6 = b.z, v7 = b.w;
    hi[0] = (__bf16)v0; lo[0] = (__bf16)(v0 - (float)hi[0]);
    hi[1] = (__bf16)v1; lo[1] = (__bf16)(v1 - (float)hi[1]);
    hi[2] = (__bf16)v2; lo[2] = (__bf16)(v2 - (float)hi[2]);
    hi[3] = (__bf16)v3; lo[3] = (__bf16)(v3 - (float)hi[3]);
    hi[4] = (__bf16)v4; lo[4] = (__bf16)(v4 - (float)hi[4]);
    hi[5] = (__bf16)v5; lo[5] = (__bf16)(v5 - (float)hi[5]);
    hi[6] = (__bf16)v6; lo[6] = (__bf16)(v6 - (float)hi[6]);
    hi[7] = (__bf16)v7; lo[7] = (__bf16)(v7 - (float)hi[7]);
}

#define MFMA(a, b, c) __builtin_amdgcn_mfma_f32_32x32x16_bf16((a), (b), (c), 0, 0, 0)
#define LD4(p) (*reinterpret_cast<const float4*>(p))

// ---- Pass 1: bf16-split MFMA. Block = 32 tokens, 4 waves K-split 512 ------
__global__ __launch_bounds__(256, 2) void moe_gate_mfma(
    const float* __restrict__ x,   // [T, H]
    const float* __restrict__ w,   // [NE, H]
    float* __restrict__ out,       // [2T idx][2T weights]
    int woff,
    int* __restrict__ wl, int wlcap)  // wl[0]=count, wl[1..]=token ids
{
    __shared__ float S[3 * 32 * 65];   // 24960 B, cross-wave reduction

    const int tid  = threadIdx.x;
    const int lane = tid & 63;
    const int wv   = tid >> 6;         // K-split index 0..3
    const int lo5  = lane & 31;
    const int hi5  = lane >> 5;
    const int t0   = blockIdx.x * 32;
    const int kb   = wv * 512;

    // frag sources: 8 consecutive k at row (lane&31), k-offset (lane>>5)*8
    const float* xp  = x + (size_t)(t0 + lo5) * H + kb + hi5 * 8;   // B: tokens
    const float* wp0 = w + (size_t)(lo5)      * H + kb + hi5 * 8;   // A: e 0..31
    const float* wp1 = w + (size_t)(32 + lo5) * H + kb + hi5 * 8;   // A: e 32..63

    f32x16 acc0, acc1;
#pragma unroll
    for (int i = 0; i < 16; ++i) { acc0[i] = 0.f; acc1[i] = 0.f; }

    // 2-stage register pipeline over 32 k-steps of 16
    float4 cxa = LD4(xp),      cxb = LD4(xp + 4);
    float4 ca0 = LD4(wp0),     cb0 = LD4(wp0 + 4);
    float4 ca1 = LD4(wp1),     cb1 = LD4(wp1 + 4);

#pragma unroll 4
    for (int s = 0; s < 32; ++s) {
        const int off = (s + 1 < 32) ? (s + 1) * 16 : 0;   // dummy-safe tail
        const float4 nxa = LD4(xp + off),  nxb = LD4(xp + off + 4);
        const float4 na0 = LD4(wp0 + off), nb0 = LD4(wp0 + off + 4);
        const float4 na1 = LD4(wp1 + off), nb1 = LD4(wp1 + off + 4);

        bf16x8 bh, bl, ah0, al0, ah1, al1;
        cvt8(cxa, cxb, bh, bl);
        cvt8(ca0, cb0, ah0, al0);
        cvt8(ca1, cb1, ah1, al1);

        acc0 = MFMA(ah0, bh, acc0);    // hi*hi
        acc1 = MFMA(ah1, bh, acc1);
        acc0 = MFMA(ah0, bl, acc0);    // hi*lo
        acc1 = MFMA(ah1, bl, acc1);
        acc0 = MFMA(al0, bh, acc0);    // lo*hi
        acc1 = MFMA(al1, bh, acc1);

        cxa = nxa; cxb = nxb; ca0 = na0; cb0 = nb0; ca1 = na1; cb1 = nb1;
    }

    // ---- K-split reduction: waves 1..3 -> LDS, wave 0 accumulates ----------
    // C layout: col(token) = lane&31, row(e_local) = (r&3)+8*(r>>2)+4*hi5
    if (wv > 0) {
        const int base = ((wv - 1) * 32 + lo5) * 65;
#pragma unroll
        for (int r = 0; r < 16; ++r) {
            const int e0 = (r & 3) + 8 * (r >> 2) + 4 * hi5;
            S[base + e0]      = acc0[r];
            S[base + 32 + e0] = acc1[r];
        }
    }
    __syncthreads();
    if (wv != 0) return;

#pragma unroll
    for (int q = 0; q < 3; ++q) {
        const int base = (q * 32 + lo5) * 65;
#pragma unroll
        for (int r = 0; r < 16; ++r) {
            const int e0 = (r & 3) + 8 * (r >> 2) + 4 * hi5;
            acc0[r] += S[base + e0];
            acc1[r] += S[base + 32 + e0];
        }
    }

    // ---- per-lane top-3 over 32 held experts (e ascending => stable) -------
    float m1 = NEGF, m2 = NEGF, m3 = NEGF;
    int   i1 = 0, i2 = 0;
#pragma unroll
    for (int r = 0; r < 16; ++r) {
        const float v = acc0[r];
        const int   e = (r & 3) + 8 * (r >> 2) + 4 * hi5;
        if (v > m1)      { m3 = m2; m2 = m1; i2 = i1; m1 = v; i1 = e; }
        else if (v > m2) { m3 = m2; m2 = v; i2 = e; }
        else if (v > m3) { m3 = v; }
    }
#pragma unroll
    for (int r = 0; r < 16; ++r) {
        const float v = acc1[r];
        const int   e = 32 + (r & 3) + 8 * (r >> 2) + 4 * hi5;
        if (v > m1)      { m3 = m2; m2 = m1; i2 = i1; m1 = v; i1 = e; }
        else if (v > m2) { m3 = m2; m2 = v; i2 = e; }
        else if (v > m3) { m3 = v; }
    }

    // ---- merge sorted triples across lane pair (l, l^32): same token -------
    const float n1 = __shfl_xor(m1, 32), n2 = __shfl_xor(m2, 32), n3 = __shfl_xor(m3, 32);
    const int   j1 = __shfl_xor(i1, 32), j2 = __shfl_xor(i2, 32);

    float a1, a2, a3, b1, b2, b3; int ia1, ia2, ib1, ib2;
    const bool aF = (m1 > n1) || (m1 == n1 && i1 < j1);
    if (aF) { a1=m1; a2=m2; a3=m3; ia1=i1; ia2=i2; b1=n1; b2=n2; b3=n3; ib1=j1; ib2=j2; }
    else    { a1=n1; a2=n2; a3=n3; ia1=j1; ia2=j2; b1=m1; b2=m2; b3=m3; ib1=i1; ib2=i2; }

    const float o1 = a1; const int oi1 = ia1;
    float o2, o3; int oi2;
    const bool a2F = (a2 > b1) || (a2 == b1 && ia2 < ib1);
    if (a2F) { o2 = a2; oi2 = ia2; o3 = (a3 > b1) ? a3 : b1; }
    else     { o2 = b1; oi2 = ib1; o3 = (a2 > b2) ? a2 : b2; }

    if (hi5 == 0) {
        const int t = t0 + lo5;
        const float r = expf(o2 - o1);       // <= 1
        const float s = 1.0f + r;
        out[2 * t + 0]        = (float)oi1;
        out[2 * t + 1]        = (float)oi2;
        out[woff + 2 * t + 0] = 1.0f / s;
        out[woff + 2 * t + 1] = r / s;
        if ((o1 - o2 < TAU) || (o2 - o3 < TAU)) {
            const int pos = atomicAdd(wl, 1);
            if (pos < wlcap) wl[1 + pos] = t;
        }
    }
}

// ---- Pass 2: fp64 refine over compacted worklist, 4-wave K-split ----------
__global__ __launch_bounds__(256) void moe_refine_fp64(
    const float* __restrict__ x, const float* __restrict__ w,
    float* __restrict__ out, int woff,
    const int* __restrict__ wl, int wlcap)
{
    __shared__ double Sd[3][NE];
    const int lane = threadIdx.x & 63;
    const int wv   = threadIdx.x >> 6;
    int cnt = wl[0];
    if (cnt > wlcap) cnt = wlcap;

    for (int i = blockIdx.x; i < cnt; i += gridDim.x) {
        const int t = wl[1 + i];
        const float* xr = x + (size_t)t * H + wv * 512;
        const float* wr = w + (size_t)lane * H + wv * 512;   // lane = expert

        double a0 = 0.0, a1 = 0.0, a2 = 0.0, a3 = 0.0;
        for (int k = 0; k < 512; k += 16) {
            const float4 wq0 = LD4(&wr[k + 0]),  wq1 = LD4(&wr[k + 4]);
            const float4 wq2 = LD4(&wr[k + 8]),  wq3 = LD4(&wr[k + 12]);
            const float4 xq0 = LD4(&xr[k + 0]),  xq1 = LD4(&xr[k + 4]);
            const float4 xq2 = LD4(&xr[k + 8]),  xq3 = LD4(&xr[k + 12]);
            a0 = fma((double)wq0.x, (double)xq0.x, a0);
            a0 = fma((double)wq0.y, (double)xq0.y, a0);
            a0 = fma((double)wq0.z, (double)xq0.z, a0);
            a0 = fma((double)wq0.w, (double)xq0.w, a0);
            a1 = fma((double)wq1.x, (double)xq1.x, a1);
            a1 = fma((double)wq1.y, (double)xq1.y, a1);
            a1 = fma((double)wq1.z, (double)xq1.z, a1);
            a1 = fma((double)wq1.w, (double)xq1.w, a1);
            a2 = fma((double)wq2.x, (double)xq2.x, a2);
            a2 = fma((double)wq2.y, (double)xq2.y, a2);
            a2 = fma((double)wq2.z, (double)xq2.z, a2);
            a2 = fma((double)wq2.w, (double)xq2.w, a2);
            a3 = fma((double)wq3.x, (double)xq3.x, a3);
            a3 = fma((double)wq3.y, (double)xq3.y, a3);
            a3 = fma((double)wq3.z, (double)xq3.z, a3);
            a3 = fma((double)wq3.w, (double)xq3.w, a3);
        }
        const double part = (a0 + a1) + (a2 + a3);

        if (wv > 0) Sd[wv - 1][lane] = part;
        __syncthreads();
        if (wv == 0) {
            const double acc = ((part + Sd[0][lane]) + Sd[1][lane]) + Sd[2][lane];

            double v = acc; int bi = lane;
#pragma unroll
            for (int off = 32; off > 0; off >>= 1) {
                double ov = __shfl_xor(v, off);
                int    oi = __shfl_xor(bi, off);
                if (ov > v || (ov == v && oi < bi)) { v = ov; bi = oi; }
            }
            const double m1 = v; const int i1 = bi;

            double v2 = (lane == i1) ? -1.0e300 : acc; int b2 = lane;
#pragma unroll
            for (int off = 32; off > 0; off >>= 1) {
                double ov = __shfl_xor(v2, off);
                int    oi = __shfl_xor(b2, off);
                if (ov > v2 || (ov == v2 && oi < b2)) { v2 = ov; b2 = oi; }
            }
            const double m2 = v2; const int i2 = b2;

            if (lane == 0) {
                const double r = exp(m2 - m1);
                const double s = 1.0 + r;
                out[2 * t + 0]        = (float)i1;
                out[2 * t + 1]        = (float)i2;
                out[woff + 2 * t + 0] = (float)(1.0 / s);
                out[woff + 2 * t + 1] = (float)(r / s);
            }
        }
        __syncthreads();   // Sd reused next iteration
    }
}

extern "C" void kernel_launch(void* const* d_in, const int* in_sizes, int n_in,
                              void* d_out, int out_size, void* d_ws, size_t ws_size,
                              hipStream_t stream) {
    const float* x   = (const float*)d_in[0];
    const float* wgt = (const float*)d_in[1];
    float* out = (float*)d_out;

    const int T    = in_sizes[0] / H;   // 16384
    const int woff = out_size / 2;      // 32768

    int* wl = (int*)d_ws;
    int wlcap = (int)(ws_size / sizeof(int)) - 1;
    if (wlcap > T) wlcap = T;

    hipMemsetAsync(wl, 0, sizeof(int), stream);   // zero the append counter

    moe_gate_mfma<<<dim3(T / 32), dim3(256), 0, stream>>>(
        x, wgt, out, woff, wl, wlcap);

    moe_refine_fp64<<<dim3(512), dim3(256), 0, stream>>>(
        x, wgt, out, woff, wl, wlcap);
}

// Round 6
// 88.603 us; speedup vs baseline: 7.4973x; 1.1497x over previous
//
#include <hip/hip_runtime.h>
#include <math.h>

#define H    2048
#define NE   64
#define TOKB 64
#define KC   64
#define NCH  (H / KC)     // 32 chunks
#define TAU  4.0e-3f
#define NEGF (-3.0e38f)

typedef __bf16 bf16x8 __attribute__((ext_vector_type(8)));
typedef float  f32x16 __attribute__((ext_vector_type(16)));

#define MFMA(a, b, c) __builtin_amdgcn_mfma_f32_32x32x16_bf16((a), (b), (c), 0, 0, 0)
#define LD4(p) (*reinterpret_cast<const float4*>(p))

// split fp32 octet (2x float4, consecutive k) into bf16 hi + lo fragments
__device__ __forceinline__ void cvt8(const float4 a, const float4 b,
                                     bf16x8& hi, bf16x8& lo) {
    const float v0 = a.x, v1 = a.y, v2 = a.z, v3 = a.w;
    const float v4 = b.x, v5 = b.y, v6 = b.z, v7 = b.w;
    hi[0] = (__bf16)v0; lo[0] = (__bf16)(v0 - (float)hi[0]);
    hi[1] = (__bf16)v1; lo[1] = (__bf16)(v1 - (float)hi[1]);
    hi[2] = (__bf16)v2; lo[2] = (__bf16)(v2 - (float)hi[2]);
    hi[3] = (__bf16)v3; lo[3] = (__bf16)(v3 - (float)hi[3]);
    hi[4] = (__bf16)v4; lo[4] = (__bf16)(v4 - (float)hi[4]);
    hi[5] = (__bf16)v5; lo[5] = (__bf16)(v5 - (float)hi[5]);
    hi[6] = (__bf16)v6; lo[6] = (__bf16)(v6 - (float)hi[6]);
    hi[7] = (__bf16)v7; lo[7] = (__bf16)(v7 - (float)hi[7]);
}

// async 16B global -> LDS (wave-uniform LDS base + lane*16)
__device__ __forceinline__ void gll16(const float* g, float* l) {
    __builtin_amdgcn_global_load_lds(
        (const __attribute__((address_space(1))) void*)g,
        (__attribute__((address_space(3))) void*)l, 16, 0, 0);
}

// ---- Pass 1: LDS-staged bf16-split MFMA ------------------------------------
// block: 512 thr / 8 waves, 64 tokens x 64 experts; wave = (mtile) x (K-quarter)
__global__ __launch_bounds__(512) void moe_gate_mfma(
    const float* __restrict__ x,   // [T, H]
    const float* __restrict__ w,   // [NE, H]
    float* __restrict__ out,       // [2T idx][2T weights]
    int woff,
    int* __restrict__ wl, int wlcap)
{
    __shared__ float lds[2][8192];    // 2 x 32KB: A=[64][64] floats 0..4095, B 4096..8191

    const int tid  = threadIdx.x;
    const int lane = tid & 63;
    const int wv   = tid >> 6;        // 0..7
    const int lo5  = lane & 31;
    const int hi5  = lane >> 5;
    const int mt   = wv >> 2;         // m-tile (token half)
    const int kq   = wv & 3;          // K-quarter within chunk
    const int t0   = blockIdx.x * TOKB;

    // ---- staging geometry: wave stages floats [wv*1024, +1024), 4 x 256 ----
    // LDS is LINEAR; global source is pre-swizzled: slot ^= (row & 15)
    const float* sbase[4];
    #pragma unroll
    for (int s = 0; s < 4; ++s) {
        const int idx = wv * 1024 + s * 256 + lane * 4;  // float index in buffer
        const int tr  = (idx & 4095) >> 6;               // row within tile 0..63
        const int sl  = (lane & 15) ^ (tr & 15);         // global slot to fetch
        sbase[s] = (idx < 4096)
            ? (w + (size_t)tr * H + sl * 4)              // A: expert row
            : (x + (size_t)(t0 + tr) * H + sl * 4);      // B: token row
    }

    f32x16 acc0, acc1;
    #pragma unroll
    for (int i = 0; i < 16; ++i) { acc0[i] = 0.f; acc1[i] = 0.f; }

    // prologue: stage chunk 0 into buffer 0
    #pragma unroll
    for (int s = 0; s < 4; ++s)
        gll16(sbase[s], &lds[0][wv * 1024 + s * 256]);
    __syncthreads();                   // implicit vmcnt(0) drains the stage

    const int kk0 = kq * 16 + hi5 * 8; // this lane's k-offset within chunk
    const int s0  = kk0 >> 2;          // (even) 16B-slot index

    for (int c = 0; c < NCH; ++c) {
        const int cur = c & 1;
        if (c + 1 < NCH) {             // issue next chunk (async, in flight)
            const int kc = (c + 1) * KC;
            #pragma unroll
            for (int s = 0; s < 4; ++s)
                gll16(sbase[s] + kc, &lds[cur ^ 1][wv * 1024 + s * 256]);
        }

        const float* buf = lds[cur];
        const int rb = mt * 32 + lo5;          // token row
        const int ra0 = lo5, ra1 = 32 + lo5;   // expert rows

        const float4 b1  = LD4(&buf[4096 + rb * 64 + ((s0     ^ (rb  & 15)) << 2)]);
        const float4 b2  = LD4(&buf[4096 + rb * 64 + (((s0+1) ^ (rb  & 15)) << 2)]);
        const float4 a01 = LD4(&buf[       ra0 * 64 + ((s0     ^ (ra0 & 15)) << 2)]);
        const float4 a02 = LD4(&buf[       ra0 * 64 + (((s0+1) ^ (ra0 & 15)) << 2)]);
        const float4 a11 = LD4(&buf[       ra1 * 64 + ((s0     ^ (ra1 & 15)) << 2)]);
        const float4 a12 = LD4(&buf[       ra1 * 64 + (((s0+1) ^ (ra1 & 15)) << 2)]);

        bf16x8 bh, bl, ah0, al0, ah1, al1;
        cvt8(b1, b2, bh, bl);
        cvt8(a01, a02, ah0, al0);
        cvt8(a11, a12, ah1, al1);

        acc0 = MFMA(ah0, bh, acc0);    // hi*hi
        acc1 = MFMA(ah1, bh, acc1);
        acc0 = MFMA(ah0, bl, acc0);    // hi*lo
        acc1 = MFMA(ah1, bl, acc1);
        acc0 = MFMA(al0, bh, acc0);    // lo*hi
        acc1 = MFMA(al1, bh, acc1);

        __syncthreads();               // drains next-chunk stage + guards reuse
    }

    // ---- K-quarter reduction: kq 1..3 write partials, kq 0 accumulates ----
    float* S = &lds[0][0];             // 12478 floats used < 16384 available
    if (kq != 0) {
        const int base = ((mt * 3 + (kq - 1)) * 32 + lo5) * 65;
        #pragma unroll
        for (int r = 0; r < 16; ++r) {
            const int e0 = (r & 3) + 8 * (r >> 2) + 4 * hi5;
            S[base + e0]      = acc0[r];
            S[base + 32 + e0] = acc1[r];
        }
    }
    __syncthreads();
    if (kq != 0) return;
    #pragma unroll
    for (int q = 0; q < 3; ++q) {
        const int base = ((mt * 3 + q) * 32 + lo5) * 65;
        #pragma unroll
        for (int r = 0; r < 16; ++r) {
            const int e0 = (r & 3) + 8 * (r >> 2) + 4 * hi5;
            acc0[r] += S[base + e0];
            acc1[r] += S[base + 32 + e0];
        }
    }

    // ---- per-lane top-3 over 32 held experts (e ascending => stable) -------
    float m1 = NEGF, m2 = NEGF, m3 = NEGF;
    int   i1 = 0, i2 = 0;
    #pragma unroll
    for (int r = 0; r < 16; ++r) {
        const float v = acc0[r];
        const int   e = (r & 3) + 8 * (r >> 2) + 4 * hi5;
        if (v > m1)      { m3 = m2; m2 = m1; i2 = i1; m1 = v; i1 = e; }
        else if (v > m2) { m3 = m2; m2 = v; i2 = e; }
        else if (v > m3) { m3 = v; }
    }
    #pragma unroll
    for (int r = 0; r < 16; ++r) {
        const float v = acc1[r];
        const int   e = 32 + (r & 3) + 8 * (r >> 2) + 4 * hi5;
        if (v > m1)      { m3 = m2; m2 = m1; i2 = i1; m1 = v; i1 = e; }
        else if (v > m2) { m3 = m2; m2 = v; i2 = e; }
        else if (v > m3) { m3 = v; }
    }

    // ---- merge sorted triples across lane pair (l, l^32): same token -------
    const float n1 = __shfl_xor(m1, 32), n2 = __shfl_xor(m2, 32), n3 = __shfl_xor(m3, 32);
    const int   j1 = __shfl_xor(i1, 32), j2 = __shfl_xor(i2, 32);

    float a1, a2, a3, b1, b2, b3; int ia1, ia2, ib1, ib2;
    const bool aF = (m1 > n1) || (m1 == n1 && i1 < j1);
    if (aF) { a1=m1; a2=m2; a3=m3; ia1=i1; ia2=i2; b1=n1; b2=n2; b3=n3; ib1=j1; ib2=j2; }
    else    { a1=n1; a2=n2; a3=n3; ia1=j1; ia2=j2; b1=m1; b2=m2; b3=m3; ib1=i1; ib2=i2; }

    const float o1 = a1; const int oi1 = ia1;
    float o2, o3; int oi2;
    const bool a2F = (a2 > b1) || (a2 == b1 && ia2 < ib1);
    if (a2F) { o2 = a2; oi2 = ia2; o3 = (a3 > b1) ? a3 : b1; }
    else     { o2 = b1; oi2 = ib1; o3 = (a2 > b2) ? a2 : b2; }

    if (hi5 == 0) {
        const int t = t0 + mt * 32 + lo5;
        const float r = expf(o2 - o1);       // <= 1
        const float s = 1.0f + r;
        out[2 * t + 0]        = (float)oi1;
        out[2 * t + 1]        = (float)oi2;
        out[woff + 2 * t + 0] = 1.0f / s;
        out[woff + 2 * t + 1] = r / s;
        if ((o1 - o2 < TAU) || (o2 - o3 < TAU)) {
            const int pos = atomicAdd(wl, 1);
            if (pos < wlcap) wl[1 + pos] = t;
        }
    }
}

// ---- Pass 2: fp64 refine over compacted worklist, 4-wave K-split ----------
__global__ __launch_bounds__(256) void moe_refine_fp64(
    const float* __restrict__ x, const float* __restrict__ w,
    float* __restrict__ out, int woff,
    const int* __restrict__ wl, int wlcap)
{
    __shared__ double Sd[3][NE];
    const int lane = threadIdx.x & 63;
    const int wv   = threadIdx.x >> 6;
    int cnt = wl[0];
    if (cnt > wlcap) cnt = wlcap;

    for (int i = blockIdx.x; i < cnt; i += gridDim.x) {
        const int t = wl[1 + i];
        const float* xr = x + (size_t)t * H + wv * 512;
        const float* wr = w + (size_t)lane * H + wv * 512;   // lane = expert

        double a0 = 0.0, a1 = 0.0, a2 = 0.0, a3 = 0.0;
        for (int k = 0; k < 512; k += 16) {
            const float4 wq0 = LD4(&wr[k + 0]),  wq1 = LD4(&wr[k + 4]);
            const float4 wq2 = LD4(&wr[k + 8]),  wq3 = LD4(&wr[k + 12]);
            const float4 xq0 = LD4(&xr[k + 0]),  xq1 = LD4(&xr[k + 4]);
            const float4 xq2 = LD4(&xr[k + 8]),  xq3 = LD4(&xr[k + 12]);
            a0 = fma((double)wq0.x, (double)xq0.x, a0);
            a0 = fma((double)wq0.y, (double)xq0.y, a0);
            a0 = fma((double)wq0.z, (double)xq0.z, a0);
            a0 = fma((double)wq0.w, (double)xq0.w, a0);
            a1 = fma((double)wq1.x, (double)xq1.x, a1);
            a1 = fma((double)wq1.y, (double)xq1.y, a1);
            a1 = fma((double)wq1.z, (double)xq1.z, a1);
            a1 = fma((double)wq1.w, (double)xq1.w, a1);
            a2 = fma((double)wq2.x, (double)xq2.x, a2);
            a2 = fma((double)wq2.y, (double)xq2.y, a2);
            a2 = fma((double)wq2.z, (double)xq2.z, a2);
            a2 = fma((double)wq2.w, (double)xq2.w, a2);
            a3 = fma((double)wq3.x, (double)xq3.x, a3);
            a3 = fma((double)wq3.y, (double)xq3.y, a3);
            a3 = fma((double)wq3.z, (double)xq3.z, a3);
            a3 = fma((double)wq3.w, (double)xq3.w, a3);
        }
        const double part = (a0 + a1) + (a2 + a3);

        if (wv > 0) Sd[wv - 1][lane] = part;
        __syncthreads();
        if (wv == 0) {
            const double acc = ((part + Sd[0][lane]) + Sd[1][lane]) + Sd[2][lane];

            double v = acc; int bi = lane;
            #pragma unroll
            for (int off = 32; off > 0; off >>= 1) {
                double ov = __shfl_xor(v, off);
                int    oi = __shfl_xor(bi, off);
                if (ov > v || (ov == v && oi < bi)) { v = ov; bi = oi; }
            }
            const double m1 = v; const int i1 = bi;

            double v2 = (lane == i1) ? -1.0e300 : acc; int b2 = lane;
            #pragma unroll
            for (int off = 32; off > 0; off >>= 1) {
                double ov = __shfl_xor(v2, off);
                int    oi = __shfl_xor(b2, off);
                if (ov > v2 || (ov == v2 && oi < b2)) { v2 = ov; b2 = oi; }
            }
            const double m2 = v2; const int i2 = b2;

            if (lane == 0) {
                const double r = exp(m2 - m1);
                const double s = 1.0 + r;
                out[2 * t + 0]        = (float)i1;
                out[2 * t + 1]        = (float)i2;
                out[woff + 2 * t + 0] = (float)(1.0 / s);
                out[woff + 2 * t + 1] = (float)(r / s);
            }
        }
        __syncthreads();   // Sd reused next iteration
    }
}

extern "C" void kernel_launch(void* const* d_in, const int* in_sizes, int n_in,
                              void* d_out, int out_size, void* d_ws, size_t ws_size,
                              hipStream_t stream) {
    const float* x   = (const float*)d_in[0];
    const float* wgt = (const float*)d_in[1];
    float* out = (float*)d_out;

    const int T    = in_sizes[0] / H;   // 16384
    const int woff = out_size / 2;      // 32768

    int* wl = (int*)d_ws;
    int wlcap = (int)(ws_size / sizeof(int)) - 1;
    if (wlcap > T) wlcap = T;

    hipMemsetAsync(wl, 0, sizeof(int), stream);

    moe_gate_mfma<<<dim3(T / TOKB), dim3(512), 0, stream>>>(
        x, wgt, out, woff, wl, wlcap);

    moe_refine_fp64<<<dim3(512), dim3(256), 0, stream>>>(
        x, wgt, out, woff, wl, wlcap);
}

// Round 7
// 88.513 us; speedup vs baseline: 7.5049x; 1.0010x over previous
//
#include <hip/hip_runtime.h>
#include <math.h>

#define H    2048
#define NE   64
#define TOKB 64
#define KC   64
#define NCH  (H / KC)     // 32 chunks
#define TAU  4.0e-3f
#define NEGF (-3.0e38f)

typedef __bf16 bf16x8 __attribute__((ext_vector_type(8)));
typedef float  f32x16 __attribute__((ext_vector_type(16)));

#define MFMA(a, b, c) __builtin_amdgcn_mfma_f32_32x32x16_bf16((a), (b), (c), 0, 0, 0)
#define LD4(p) (*reinterpret_cast<const float4*>(p))

// split fp32 octet (2x float4, consecutive k) into bf16 hi + lo fragments
__device__ __forceinline__ void cvt8(const float4 a, const float4 b,
                                     bf16x8& hi, bf16x8& lo) {
    const float v0 = a.x, v1 = a.y, v2 = a.z, v3 = a.w;
    const float v4 = b.x, v5 = b.y, v6 = b.z, v7 = b.w;
    hi[0] = (__bf16)v0; lo[0] = (__bf16)(v0 - (float)hi[0]);
    hi[1] = (__bf16)v1; lo[1] = (__bf16)(v1 - (float)hi[1]);
    hi[2] = (__bf16)v2; lo[2] = (__bf16)(v2 - (float)hi[2]);
    hi[3] = (__bf16)v3; lo[3] = (__bf16)(v3 - (float)hi[3]);
    hi[4] = (__bf16)v4; lo[4] = (__bf16)(v4 - (float)hi[4]);
    hi[5] = (__bf16)v5; lo[5] = (__bf16)(v5 - (float)hi[5]);
    hi[6] = (__bf16)v6; lo[6] = (__bf16)(v6 - (float)hi[6]);
    hi[7] = (__bf16)v7; lo[7] = (__bf16)(v7 - (float)hi[7]);
}

// async 16B global -> LDS (wave-uniform LDS base + lane*16)
__device__ __forceinline__ void gll16(const float* g, float* l) {
    __builtin_amdgcn_global_load_lds(
        (const __attribute__((address_space(1))) void*)g,
        (__attribute__((address_space(3))) void*)l, 16, 0, 0);
}

// ---- Pass 0: zero the worklist counter (replaces 75us memset node) --------
__global__ void zero_wl(int* __restrict__ wl) {
    if (threadIdx.x == 0) wl[0] = 0;
}

// ---- Pass 1: LDS-staged bf16-split MFMA ------------------------------------
// block: 512 thr / 8 waves, 64 tokens x 64 experts; wave = (mtile) x (K-quarter)
__global__ __launch_bounds__(512) void moe_gate_mfma(
    const float* __restrict__ x,   // [T, H]
    const float* __restrict__ w,   // [NE, H]
    float* __restrict__ out,       // [2T idx][2T weights]
    int woff,
    int* __restrict__ wl, int wlcap)
{
    __shared__ float lds[2][8192];    // 2 x 32KB: A=[64][64] floats 0..4095, B 4096..8191

    const int tid  = threadIdx.x;
    const int lane = tid & 63;
    const int wv   = tid >> 6;        // 0..7
    const int lo5  = lane & 31;
    const int hi5  = lane >> 5;
    const int mt   = wv >> 2;         // m-tile (token half)
    const int kq   = wv & 3;          // K-quarter within chunk
    const int t0   = blockIdx.x * TOKB;

    // ---- staging geometry: wave stages floats [wv*1024, +1024), 4 x 256 ----
    // LDS is LINEAR; global source is pre-swizzled: slot ^= (row & 15)
    const float* sbase[4];
    #pragma unroll
    for (int s = 0; s < 4; ++s) {
        const int idx = wv * 1024 + s * 256 + lane * 4;  // float index in buffer
        const int tr  = (idx & 4095) >> 6;               // row within tile 0..63
        const int sl  = (lane & 15) ^ (tr & 15);         // global slot to fetch
        sbase[s] = (idx < 4096)
            ? (w + (size_t)tr * H + sl * 4)              // A: expert row
            : (x + (size_t)(t0 + tr) * H + sl * 4);      // B: token row
    }

    f32x16 acc0, acc1;
    #pragma unroll
    for (int i = 0; i < 16; ++i) { acc0[i] = 0.f; acc1[i] = 0.f; }

    // prologue: stage chunk 0 into buffer 0
    #pragma unroll
    for (int s = 0; s < 4; ++s)
        gll16(sbase[s], &lds[0][wv * 1024 + s * 256]);
    __syncthreads();                   // implicit vmcnt(0) drains the stage

    const int kk0 = kq * 16 + hi5 * 8; // this lane's k-offset within chunk
    const int s0  = kk0 >> 2;          // (even) 16B-slot index

    for (int c = 0; c < NCH; ++c) {
        const int cur = c & 1;
        if (c + 1 < NCH) {             // issue next chunk (async, in flight)
            const int kc = (c + 1) * KC;
            #pragma unroll
            for (int s = 0; s < 4; ++s)
                gll16(sbase[s] + kc, &lds[cur ^ 1][wv * 1024 + s * 256]);
        }

        const float* buf = lds[cur];
        const int rb = mt * 32 + lo5;          // token row
        const int ra0 = lo5, ra1 = 32 + lo5;   // expert rows

        const float4 b1  = LD4(&buf[4096 + rb * 64 + ((s0     ^ (rb  & 15)) << 2)]);
        const float4 b2  = LD4(&buf[4096 + rb * 64 + (((s0+1) ^ (rb  & 15)) << 2)]);
        const float4 a01 = LD4(&buf[       ra0 * 64 + ((s0     ^ (ra0 & 15)) << 2)]);
        const float4 a02 = LD4(&buf[       ra0 * 64 + (((s0+1) ^ (ra0 & 15)) << 2)]);
        const float4 a11 = LD4(&buf[       ra1 * 64 + ((s0     ^ (ra1 & 15)) << 2)]);
        const float4 a12 = LD4(&buf[       ra1 * 64 + (((s0+1) ^ (ra1 & 15)) << 2)]);

        bf16x8 bh, bl, ah0, al0, ah1, al1;
        cvt8(b1, b2, bh, bl);
        cvt8(a01, a02, ah0, al0);
        cvt8(a11, a12, ah1, al1);

        acc0 = MFMA(ah0, bh, acc0);    // hi*hi
        acc1 = MFMA(ah1, bh, acc1);
        acc0 = MFMA(ah0, bl, acc0);    // hi*lo
        acc1 = MFMA(ah1, bl, acc1);
        acc0 = MFMA(al0, bh, acc0);    // lo*hi
        acc1 = MFMA(al1, bh, acc1);

        __syncthreads();               // drains next-chunk stage + guards reuse
    }

    // ---- K-quarter reduction: kq 1..3 write partials, kq 0 accumulates ----
    float* S = &lds[0][0];             // 12478 floats used < 16384 available
    if (kq != 0) {
        const int base = ((mt * 3 + (kq - 1)) * 32 + lo5) * 65;
        #pragma unroll
        for (int r = 0; r < 16; ++r) {
            const int e0 = (r & 3) + 8 * (r >> 2) + 4 * hi5;
            S[base + e0]      = acc0[r];
            S[base + 32 + e0] = acc1[r];
        }
    }
    __syncthreads();
    if (kq != 0) return;
    #pragma unroll
    for (int q = 0; q < 3; ++q) {
        const int base = ((mt * 3 + q) * 32 + lo5) * 65;
        #pragma unroll
        for (int r = 0; r < 16; ++r) {
            const int e0 = (r & 3) + 8 * (r >> 2) + 4 * hi5;
            acc0[r] += S[base + e0];
            acc1[r] += S[base + 32 + e0];
        }
    }

    // ---- per-lane top-3 over 32 held experts (e ascending => stable) -------
    float m1 = NEGF, m2 = NEGF, m3 = NEGF;
    int   i1 = 0, i2 = 0;
    #pragma unroll
    for (int r = 0; r < 16; ++r) {
        const float v = acc0[r];
        const int   e = (r & 3) + 8 * (r >> 2) + 4 * hi5;
        if (v > m1)      { m3 = m2; m2 = m1; i2 = i1; m1 = v; i1 = e; }
        else if (v > m2) { m3 = m2; m2 = v; i2 = e; }
        else if (v > m3) { m3 = v; }
    }
    #pragma unroll
    for (int r = 0; r < 16; ++r) {
        const float v = acc1[r];
        const int   e = 32 + (r & 3) + 8 * (r >> 2) + 4 * hi5;
        if (v > m1)      { m3 = m2; m2 = m1; i2 = i1; m1 = v; i1 = e; }
        else if (v > m2) { m3 = m2; m2 = v; i2 = e; }
        else if (v > m3) { m3 = v; }
    }

    // ---- merge sorted triples across lane pair (l, l^32): same token -------
    const float n1 = __shfl_xor(m1, 32), n2 = __shfl_xor(m2, 32), n3 = __shfl_xor(m3, 32);
    const int   j1 = __shfl_xor(i1, 32), j2 = __shfl_xor(i2, 32);

    float a1, a2, a3, b1, b2, b3; int ia1, ia2, ib1, ib2;
    const bool aF = (m1 > n1) || (m1 == n1 && i1 < j1);
    if (aF) { a1=m1; a2=m2; a3=m3; ia1=i1; ia2=i2; b1=n1; b2=n2; b3=n3; ib1=j1; ib2=j2; }
    else    { a1=n1; a2=n2; a3=n3; ia1=j1; ia2=j2; b1=m1; b2=m2; b3=m3; ib1=i1; ib2=i2; }

    const float o1 = a1; const int oi1 = ia1;
    float o2, o3; int oi2;
    const bool a2F = (a2 > b1) || (a2 == b1 && ia2 < ib1);
    if (a2F) { o2 = a2; oi2 = ia2; o3 = (a3 > b1) ? a3 : b1; }
    else     { o2 = b1; oi2 = ib1; o3 = (a2 > b2) ? a2 : b2; }

    if (hi5 == 0) {
        const int t = t0 + mt * 32 + lo5;
        const float r = expf(o2 - o1);       // <= 1
        const float s = 1.0f + r;
        out[2 * t + 0]        = (float)oi1;
        out[2 * t + 1]        = (float)oi2;
        out[woff + 2 * t + 0] = 1.0f / s;
        out[woff + 2 * t + 1] = r / s;
        if ((o1 - o2 < TAU) || (o2 - o3 < TAU)) {
            const int pos = atomicAdd(wl, 1);
            if (pos < wlcap) wl[1 + pos] = t;
        }
    }
}

// ---- Pass 2: fp64 refine over compacted worklist, 4-wave K-split ----------
__global__ __launch_bounds__(256) void moe_refine_fp64(
    const float* __restrict__ x, const float* __restrict__ w,
    float* __restrict__ out, int woff,
    const int* __restrict__ wl, int wlcap)
{
    __shared__ double Sd[3][NE];
    const int lane = threadIdx.x & 63;
    const int wv   = threadIdx.x >> 6;
    int cnt = wl[0];
    if (cnt > wlcap) cnt = wlcap;

    for (int i = blockIdx.x; i < cnt; i += gridDim.x) {
        const int t = wl[1 + i];
        const float* xr = x + (size_t)t * H + wv * 512;
        const float* wr = w + (size_t)lane * H + wv * 512;   // lane = expert

        double a0 = 0.0, a1 = 0.0, a2 = 0.0, a3 = 0.0;
        for (int k = 0; k < 512; k += 16) {
            const float4 wq0 = LD4(&wr[k + 0]),  wq1 = LD4(&wr[k + 4]);
            const float4 wq2 = LD4(&wr[k + 8]),  wq3 = LD4(&wr[k + 12]);
            const float4 xq0 = LD4(&xr[k + 0]),  xq1 = LD4(&xr[k + 4]);
            const float4 xq2 = LD4(&xr[k + 8]),  xq3 = LD4(&xr[k + 12]);
            a0 = fma((double)wq0.x, (double)xq0.x, a0);
            a0 = fma((double)wq0.y, (double)xq0.y, a0);
            a0 = fma((double)wq0.z, (double)xq0.z, a0);
            a0 = fma((double)wq0.w, (double)xq0.w, a0);
            a1 = fma((double)wq1.x, (double)xq1.x, a1);
            a1 = fma((double)wq1.y, (double)xq1.y, a1);
            a1 = fma((double)wq1.z, (double)xq1.z, a1);
            a1 = fma((double)wq1.w, (double)xq1.w, a1);
            a2 = fma((double)wq2.x, (double)xq2.x, a2);
            a2 = fma((double)wq2.y, (double)xq2.y, a2);
            a2 = fma((double)wq2.z, (double)xq2.z, a2);
            a2 = fma((double)wq2.w, (double)xq2.w, a2);
            a3 = fma((double)wq3.x, (double)xq3.x, a3);
            a3 = fma((double)wq3.y, (double)xq3.y, a3);
            a3 = fma((double)wq3.z, (double)xq3.z, a3);
            a3 = fma((double)wq3.w, (double)xq3.w, a3);
        }
        const double part = (a0 + a1) + (a2 + a3);

        if (wv > 0) Sd[wv - 1][lane] = part;
        __syncthreads();
        if (wv == 0) {
            const double acc = ((part + Sd[0][lane]) + Sd[1][lane]) + Sd[2][lane];

            double v = acc; int bi = lane;
            #pragma unroll
            for (int off = 32; off > 0; off >>= 1) {
                double ov = __shfl_xor(v, off);
                int    oi = __shfl_xor(bi, off);
                if (ov > v || (ov == v && oi < bi)) { v = ov; bi = oi; }
            }
            const double m1 = v; const int i1 = bi;

            double v2 = (lane == i1) ? -1.0e300 : acc; int b2 = lane;
            #pragma unroll
            for (int off = 32; off > 0; off >>= 1) {
                double ov = __shfl_xor(v2, off);
                int    oi = __shfl_xor(b2, off);
                if (ov > v2 || (ov == v2 && oi < b2)) { v2 = ov; b2 = oi; }
            }
            const double m2 = v2; const int i2 = b2;

            if (lane == 0) {
                const double r = exp(m2 - m1);
                const double s = 1.0 + r;
                out[2 * t + 0]        = (float)i1;
                out[2 * t + 1]        = (float)i2;
                out[woff + 2 * t + 0] = (float)(1.0 / s);
                out[woff + 2 * t + 1] = (float)(r / s);
            }
        }
        __syncthreads();   // Sd reused next iteration
    }
}

extern "C" void kernel_launch(void* const* d_in, const int* in_sizes, int n_in,
                              void* d_out, int out_size, void* d_ws, size_t ws_size,
                              hipStream_t stream) {
    const float* x   = (const float*)d_in[0];
    const float* wgt = (const float*)d_in[1];
    float* out = (float*)d_out;

    const int T    = in_sizes[0] / H;   // 16384
    const int woff = out_size / 2;      // 32768

    int* wl = (int*)d_ws;
    int wlcap = (int)(ws_size / sizeof(int)) - 1;
    if (wlcap > T) wlcap = T;

    zero_wl<<<dim3(1), dim3(64), 0, stream>>>(wl);

    moe_gate_mfma<<<dim3(T / TOKB), dim3(512), 0, stream>>>(
        x, wgt, out, woff, wl, wlcap);

    moe_refine_fp64<<<dim3(512), dim3(256), 0, stream>>>(
        x, wgt, out, woff, wl, wlcap);
}

// Round 8
// 74.565 us; speedup vs baseline: 8.9088x; 1.1871x over previous
//
#include <hip/hip_runtime.h>
#include <math.h>

#define H    2048
#define NE   64
#define TOKB 32
#define KC   64
#define NCH  (H / KC)     // 32 chunks
#define TAU  4.0e-3f
#define NEGF (-3.0e38f)

typedef __bf16 bf16x8 __attribute__((ext_vector_type(8)));
typedef float  f32x16 __attribute__((ext_vector_type(16)));

#define MFMA(a, b, c) __builtin_amdgcn_mfma_f32_32x32x16_bf16((a), (b), (c), 0, 0, 0)
#define LD4(p) (*reinterpret_cast<const float4*>(p))

// split fp32 octet (2x float4, consecutive k) into bf16 hi + lo fragments
__device__ __forceinline__ void cvt8(const float4 a, const float4 b,
                                     bf16x8& hi, bf16x8& lo) {
    const float v0 = a.x, v1 = a.y, v2 = a.z, v3 = a.w;
    const float v4 = b.x, v5 = b.y, v6 = b.z, v7 = b.w;
    hi[0] = (__bf16)v0; lo[0] = (__bf16)(v0 - (float)hi[0]);
    hi[1] = (__bf16)v1; lo[1] = (__bf16)(v1 - (float)hi[1]);
    hi[2] = (__bf16)v2; lo[2] = (__bf16)(v2 - (float)hi[2]);
    hi[3] = (__bf16)v3; lo[3] = (__bf16)(v3 - (float)hi[3]);
    hi[4] = (__bf16)v4; lo[4] = (__bf16)(v4 - (float)hi[4]);
    hi[5] = (__bf16)v5; lo[5] = (__bf16)(v5 - (float)hi[5]);
    hi[6] = (__bf16)v6; lo[6] = (__bf16)(v6 - (float)hi[6]);
    hi[7] = (__bf16)v7; lo[7] = (__bf16)(v7 - (float)hi[7]);
}

// async 16B global -> LDS (wave-uniform LDS base + lane*16)
__device__ __forceinline__ void gll16(const float* g, float* l) {
    __builtin_amdgcn_global_load_lds(
        (const __attribute__((address_space(1))) void*)g,
        (__attribute__((address_space(3))) void*)l, 16, 0, 0);
}

// ---- Pass 0: zero the worklist counter ------------------------------------
__global__ void zero_wl(int* __restrict__ wl) {
    if (threadIdx.x == 0) wl[0] = 0;
}

// ---- Pass 1: LDS-staged bf16-split MFMA ------------------------------------
// block: 256 thr / 4 waves (wave = K-quarter), 32 tokens x 64 experts.
// grid 512 = 2 blocks/CU: second block computes while first drains its barrier.
__global__ __launch_bounds__(256) void moe_gate_mfma(
    const float* __restrict__ x,   // [T, H]
    const float* __restrict__ w,   // [NE, H]
    float* __restrict__ out,       // [2T idx][2T weights]
    int woff,
    int* __restrict__ wl, int wlcap)
{
    __shared__ float lds[2][6144];    // 2 x 24KB: A=[64][64] floats 0..4095, B=[32][64] 4096..6143

    const int tid  = threadIdx.x;
    const int lane = tid & 63;
    const int kq   = tid >> 6;        // K-quarter 0..3
    const int lo5  = lane & 31;
    const int hi5  = lane >> 5;
    const int t0   = blockIdx.x * TOKB;

    // ---- staging geometry: wave stages floats [kq*1536, +1536), 6 x 256 ----
    // LDS is LINEAR; global source is pre-swizzled: slot ^= (row & 15)
    const float* sbase[6];
    #pragma unroll
    for (int s = 0; s < 6; ++s) {
        const int idx = kq * 1536 + s * 256 + lane * 4;  // float index in buffer
        const int tr  = (idx & 4095) >> 6;               // row within tile
        const int sl  = (lane & 15) ^ (tr & 15);         // pre-swizzled slot
        sbase[s] = (idx < 4096)
            ? (w + (size_t)tr * H + sl * 4)              // A: expert row 0..63
            : (x + (size_t)(t0 + tr) * H + sl * 4);      // B: token row 0..31
    }

    f32x16 acc0, acc1;
    #pragma unroll
    for (int i = 0; i < 16; ++i) { acc0[i] = 0.f; acc1[i] = 0.f; }

    // prologue: stage chunk 0 into buffer 0
    #pragma unroll
    for (int s = 0; s < 6; ++s)
        gll16(sbase[s], &lds[0][kq * 1536 + s * 256]);
    __syncthreads();

    const int s0 = kq * 4 + hi5 * 2;   // this lane's 16B-slot in a 64-float row

    for (int c = 0; c < NCH; ++c) {
        const int cur = c & 1;
        if (c + 1 < NCH) {             // issue next chunk (async, in flight)
            const int kc = (c + 1) * KC;
            #pragma unroll
            for (int s = 0; s < 6; ++s)
                gll16(sbase[s] + kc, &lds[cur ^ 1][kq * 1536 + s * 256]);
        }

        const float* buf = lds[cur];
        const int rb  = lo5;                   // token row
        const int ra0 = lo5, ra1 = 32 + lo5;   // expert rows

        const float4 b1  = LD4(&buf[4096 + rb * 64 + ((s0     ^ (rb  & 15)) << 2)]);
        const float4 b2  = LD4(&buf[4096 + rb * 64 + (((s0+1) ^ (rb  & 15)) << 2)]);
        const float4 a01 = LD4(&buf[       ra0 * 64 + ((s0     ^ (ra0 & 15)) << 2)]);
        const float4 a02 = LD4(&buf[       ra0 * 64 + (((s0+1) ^ (ra0 & 15)) << 2)]);
        const float4 a11 = LD4(&buf[       ra1 * 64 + ((s0     ^ (ra1 & 15)) << 2)]);
        const float4 a12 = LD4(&buf[       ra1 * 64 + (((s0+1) ^ (ra1 & 15)) << 2)]);

        bf16x8 bh, bl, ah0, al0, ah1, al1;
        cvt8(b1, b2, bh, bl);
        cvt8(a01, a02, ah0, al0);
        cvt8(a11, a12, ah1, al1);

        acc0 = MFMA(ah0, bh, acc0);    // hi*hi
        acc1 = MFMA(ah1, bh, acc1);
        acc0 = MFMA(ah0, bl, acc0);    // hi*lo
        acc1 = MFMA(ah1, bl, acc1);
        acc0 = MFMA(al0, bh, acc0);    // lo*hi
        acc1 = MFMA(al1, bh, acc1);

        __syncthreads();               // drains stage + guards buffer reuse
    }

    // ---- K-quarter reduction: kq 1..3 write partials, kq 0 accumulates ----
    float* S = &lds[0][0];             // 6240 floats used < 12288 available
    if (kq != 0) {
        const int base = ((kq - 1) * 32 + lo5) * 65;
        #pragma unroll
        for (int r = 0; r < 16; ++r) {
            const int e0 = (r & 3) + 8 * (r >> 2) + 4 * hi5;
            S[base + e0]      = acc0[r];
            S[base + 32 + e0] = acc1[r];
        }
    }
    __syncthreads();
    if (kq != 0) return;
    #pragma unroll
    for (int q = 0; q < 3; ++q) {
        const int base = (q * 32 + lo5) * 65;
        #pragma unroll
        for (int r = 0; r < 16; ++r) {
            const int e0 = (r & 3) + 8 * (r >> 2) + 4 * hi5;
            acc0[r] += S[base + e0];
            acc1[r] += S[base + 32 + e0];
        }
    }

    // ---- per-lane top-3 over 32 held experts (e ascending => stable) -------
    float m1 = NEGF, m2 = NEGF, m3 = NEGF;
    int   i1 = 0, i2 = 0;
    #pragma unroll
    for (int r = 0; r < 16; ++r) {
        const float v = acc0[r];
        const int   e = (r & 3) + 8 * (r >> 2) + 4 * hi5;
        if (v > m1)      { m3 = m2; m2 = m1; i2 = i1; m1 = v; i1 = e; }
        else if (v > m2) { m3 = m2; m2 = v; i2 = e; }
        else if (v > m3) { m3 = v; }
    }
    #pragma unroll
    for (int r = 0; r < 16; ++r) {
        const float v = acc1[r];
        const int   e = 32 + (r & 3) + 8 * (r >> 2) + 4 * hi5;
        if (v > m1)      { m3 = m2; m2 = m1; i2 = i1; m1 = v; i1 = e; }
        else if (v > m2) { m3 = m2; m2 = v; i2 = e; }
        else if (v > m3) { m3 = v; }
    }

    // ---- merge sorted triples across lane pair (l, l^32): same token -------
    const float n1 = __shfl_xor(m1, 32), n2 = __shfl_xor(m2, 32), n3 = __shfl_xor(m3, 32);
    const int   j1 = __shfl_xor(i1, 32), j2 = __shfl_xor(i2, 32);

    float a1, a2, a3, b1, b2, b3; int ia1, ia2, ib1, ib2;
    const bool aF = (m1 > n1) || (m1 == n1 && i1 < j1);
    if (aF) { a1=m1; a2=m2; a3=m3; ia1=i1; ia2=i2; b1=n1; b2=n2; b3=n3; ib1=j1; ib2=j2; }
    else    { a1=n1; a2=n2; a3=n3; ia1=j1; ia2=j2; b1=m1; b2=m2; b3=m3; ib1=i1; ib2=i2; }

    const float o1 = a1; const int oi1 = ia1;
    float o2, o3; int oi2;
    const bool a2F = (a2 > b1) || (a2 == b1 && ia2 < ib1);
    if (a2F) { o2 = a2; oi2 = ia2; o3 = (a3 > b1) ? a3 : b1; }
    else     { o2 = b1; oi2 = ib1; o3 = (a2 > b2) ? a2 : b2; }

    if (hi5 == 0) {
        const int t = t0 + lo5;
        const float r = expf(o2 - o1);       // <= 1
        const float s = 1.0f + r;
        out[2 * t + 0]        = (float)oi1;
        out[2 * t + 1]        = (float)oi2;
        out[woff + 2 * t + 0] = 1.0f / s;
        out[woff + 2 * t + 1] = r / s;
        if ((o1 - o2 < TAU) || (o2 - o3 < TAU)) {
            const int pos = atomicAdd(wl, 1);
            if (pos < wlcap) wl[1 + pos] = t;
        }
    }
}

// ---- Pass 2: fp64 refine, coalesced-W, block per token, 4-wave K-split ----
__global__ __launch_bounds__(256) void moe_refine_fp64(
    const float* __restrict__ x, const float* __restrict__ w,
    float* __restrict__ out, int woff,
    const int* __restrict__ wl, int wlcap)
{
    __shared__ double Sd[3][NE];
    const int lane = threadIdx.x & 63;
    const int wv   = threadIdx.x >> 6;
    const int ks   = wv * 512;                 // this wave's K slice
    int cnt = wl[0];
    if (cnt > wlcap) cnt = wlcap;

    for (int i = blockIdx.x; i < cnt; i += gridDim.x) {
        const int t = wl[1 + i];

        // preload this wave's x slice into fp64 registers (reused by all 64 e)
        const float4 xa = LD4(&x[(size_t)t * H + ks + lane * 4]);
        const float4 xb = LD4(&x[(size_t)t * H + ks + 256 + lane * 4]);
        const double x0 = xa.x, x1 = xa.y, x2 = xa.z, x3 = xa.w;
        const double x4 = xb.x, x5 = xb.y, x6 = xb.z, x7 = xb.w;

        double myacc = 0.0;                    // this lane's expert partial
        #pragma unroll 4
        for (int e = 0; e < NE; ++e) {
            const float4 wa = LD4(&w[(size_t)e * H + ks + lane * 4]);
            const float4 wb = LD4(&w[(size_t)e * H + ks + 256 + lane * 4]);
            double sA = 0.0, sB = 0.0;
            sA = fma((double)wa.x, x0, sA); sA = fma((double)wa.y, x1, sA);
            sA = fma((double)wa.z, x2, sA); sA = fma((double)wa.w, x3, sA);
            sB = fma((double)wb.x, x4, sB); sB = fma((double)wb.y, x5, sB);
            sB = fma((double)wb.z, x6, sB); sB = fma((double)wb.w, x7, sB);
            double s = sA + sB;
            #pragma unroll
            for (int off = 1; off < 64; off <<= 1)
                s += __shfl_xor(s, off);       // all lanes -> identical total
            if (lane == e) myacc = s;
        }

        if (wv > 0) Sd[wv - 1][lane] = myacc;
        __syncthreads();
        if (wv == 0) {
            const double acc = ((myacc + Sd[0][lane]) + Sd[1][lane]) + Sd[2][lane];

            double v = acc; int bi = lane;
            #pragma unroll
            for (int off = 32; off > 0; off >>= 1) {
                double ov = __shfl_xor(v, off);
                int    oi = __shfl_xor(bi, off);
                if (ov > v || (ov == v && oi < bi)) { v = ov; bi = oi; }
            }
            const double m1 = v; const int i1 = bi;

            double v2 = (lane == i1) ? -1.0e300 : acc; int b2 = lane;
            #pragma unroll
            for (int off = 32; off > 0; off >>= 1) {
                double ov = __shfl_xor(v2, off);
                int    oi = __shfl_xor(b2, off);
                if (ov > v2 || (ov == v2 && oi < b2)) { v2 = ov; b2 = oi; }
            }
            const double m2 = v2; const int i2 = b2;

            if (lane == 0) {
                const double r = exp(m2 - m1);
                const double s = 1.0 + r;
                out[2 * t + 0]        = (float)i1;
                out[2 * t + 1]        = (float)i2;
                out[woff + 2 * t + 0] = (float)(1.0 / s);
                out[woff + 2 * t + 1] = (float)(r / s);
            }
        }
        __syncthreads();   // Sd reused next iteration
    }
}

extern "C" void kernel_launch(void* const* d_in, const int* in_sizes, int n_in,
                              void* d_out, int out_size, void* d_ws, size_t ws_size,
                              hipStream_t stream) {
    const float* x   = (const float*)d_in[0];
    const float* wgt = (const float*)d_in[1];
    float* out = (float*)d_out;

    const int T    = in_sizes[0] / H;   // 16384
    const int woff = out_size / 2;      // 32768

    int* wl = (int*)d_ws;
    int wlcap = (int)(ws_size / sizeof(int)) - 1;
    if (wlcap > T) wlcap = T;

    zero_wl<<<dim3(1), dim3(64), 0, stream>>>(wl);

    moe_gate_mfma<<<dim3(T / TOKB), dim3(256), 0, stream>>>(
        x, wgt, out, woff, wl, wlcap);

    moe_refine_fp64<<<dim3(512), dim3(256), 0, stream>>>(
        x, wgt, out, woff, wl, wlcap);
}

// Round 9
// 64.660 us; speedup vs baseline: 10.2735x; 1.1532x over previous
//
#include <hip/hip_runtime.h>
#include <math.h>

#define H    2048
#define NE   64
#define TOKB 64
#define KC   32
#define NCH  (H / KC)     // 64 chunks
#define NBUF 3
#define TAU  4.0e-3f
#define NEGF (-3.0e38f)

typedef __bf16 bf16x8 __attribute__((ext_vector_type(8)));
typedef float  f32x16 __attribute__((ext_vector_type(16)));

#define MFMA(a, b, c) __builtin_amdgcn_mfma_f32_32x32x16_bf16((a), (b), (c), 0, 0, 0)
#define LD4(p) (*reinterpret_cast<const float4*>(p))

// split fp32 octet (2x float4, consecutive k) into bf16 hi + lo fragments
__device__ __forceinline__ void cvt8(const float4 a, const float4 b,
                                     bf16x8& hi, bf16x8& lo) {
    const float v0 = a.x, v1 = a.y, v2 = a.z, v3 = a.w;
    const float v4 = b.x, v5 = b.y, v6 = b.z, v7 = b.w;
    hi[0] = (__bf16)v0; lo[0] = (__bf16)(v0 - (float)hi[0]);
    hi[1] = (__bf16)v1; lo[1] = (__bf16)(v1 - (float)hi[1]);
    hi[2] = (__bf16)v2; lo[2] = (__bf16)(v2 - (float)hi[2]);
    hi[3] = (__bf16)v3; lo[3] = (__bf16)(v3 - (float)hi[3]);
    hi[4] = (__bf16)v4; lo[4] = (__bf16)(v4 - (float)hi[4]);
    hi[5] = (__bf16)v5; lo[5] = (__bf16)(v5 - (float)hi[5]);
    hi[6] = (__bf16)v6; lo[6] = (__bf16)(v6 - (float)hi[6]);
    hi[7] = (__bf16)v7; lo[7] = (__bf16)(v7 - (float)hi[7]);
}

// async 16B global -> LDS (wave-uniform LDS base + lane*16)
__device__ __forceinline__ void gll16(const float* g, float* l) {
    __builtin_amdgcn_global_load_lds(
        (const __attribute__((address_space(1))) void*)g,
        (__attribute__((address_space(3))) void*)l, 16, 0, 0);
}

// ---- Pass 0: zero the worklist counter ------------------------------------
__global__ void zero_wl(int* __restrict__ wl) {
    if (threadIdx.x == 0) wl[0] = 0;
}

// ---- Pass 1: counted-vmcnt pipelined bf16-split MFMA -----------------------
// block: 256 thr / 4 waves = (m-half) x (K-half); 64 tokens x 64 experts.
// Per chunk (KC=32): wave computes K=16 slice; raw s_barrier + vmcnt(4)
// (never 0 in-loop) keeps next-chunk loads in flight across the barrier.
__global__ __launch_bounds__(256) void moe_gate_mfma(
    const float* __restrict__ x,   // [T, H]
    const float* __restrict__ w,   // [NE, H]
    float* __restrict__ out,       // [2T idx][2T weights]
    int woff,
    int* __restrict__ wl, int wlcap)
{
    __shared__ float lds[NBUF][4096];   // 48 KB: per buf, A=[64][32] @0, B=[64][32] @2048

    const int tid  = threadIdx.x;
    const int lane = tid & 63;
    const int wv   = tid >> 6;        // 0..3
    const int mt   = wv >> 1;         // token half
    const int kh   = wv & 1;          // K half of each chunk
    const int lo5  = lane & 31;
    const int hi5  = lane >> 5;
    const int t0   = blockIdx.x * TOKB;

    // ---- staging: wave stages floats [wv*1024, +1024) of buffer, 4 x 256 ---
    // LDS LINEAR; source pre-swizzled: slot(16B) ^= row&7 within 32-float row
    const float* sbase[4];
    #pragma unroll
    for (int s = 0; s < 4; ++s) {
        const int idx = (wv * 4 + s) * 256 + lane * 4;   // float idx in buffer
        const int tr  = (idx & 2047) >> 5;               // row within tile 0..63
        const int sl  = ((idx >> 2) & 7) ^ (tr & 7);     // swizzled source slot
        sbase[s] = (idx < 2048)
            ? (w + (size_t)tr * H + sl * 4)              // A: expert row
            : (x + (size_t)(t0 + tr) * H + sl * 4);      // B: token row
    }

    f32x16 acc0, acc1;
    #pragma unroll
    for (int i = 0; i < 16; ++i) { acc0[i] = 0.f; acc1[i] = 0.f; }

    // prologue: stage chunks 0,1 into bufs 0,1 (8 loads outstanding)
    #pragma unroll
    for (int s = 0; s < 4; ++s) gll16(sbase[s],      &lds[0][(wv * 4 + s) * 256]);
    #pragma unroll
    for (int s = 0; s < 4; ++s) gll16(sbase[s] + KC, &lds[1][(wv * 4 + s) * 256]);

    const int s0  = kh * 4 + hi5 * 2;      // lane's first 16B slot (of 8/row)
    const int xk  = lo5 & 7;               // XOR key (same for rb/ra0/ra1)
    const int rb  = mt * 32 + lo5;         // B token row
    const int ra0 = lo5, ra1 = 32 + lo5;   // A expert rows
    const int obB  = 2048 + rb * 32;
    const int obA0 = ra0 * 32, obA1 = ra1 * 32;
    const int c0 = ((s0)     ^ xk) << 2;
    const int c1 = ((s0 + 1) ^ xk) << 2;

    int ib = 0, iw = 2;                    // compute buf, issue buf (c+2)
    for (int c = 0; c < NCH; ++c) {
        if (c < NCH - 1) {
            asm volatile("s_waitcnt vmcnt(4)" ::: "memory");  // chunk c landed
        } else {
            asm volatile("s_waitcnt vmcnt(0)" ::: "memory");  // final chunk
        }
        __builtin_amdgcn_s_barrier();      // all waves' chunk-c stages done

        const float* buf = lds[ib];
        const float4 b1  = LD4(&buf[obB  + c0]);
        const float4 b2  = LD4(&buf[obB  + c1]);
        const float4 a01 = LD4(&buf[obA0 + c0]);
        const float4 a02 = LD4(&buf[obA0 + c1]);
        const float4 a11 = LD4(&buf[obA1 + c0]);
        const float4 a12 = LD4(&buf[obA1 + c1]);

        bf16x8 bh, bl, ah0, al0, ah1, al1;
        cvt8(b1, b2, bh, bl);
        cvt8(a01, a02, ah0, al0);
        cvt8(a11, a12, ah1, al1);

        acc0 = MFMA(ah0, bh, acc0);        // hi*hi
        acc1 = MFMA(ah1, bh, acc1);
        acc0 = MFMA(ah0, bl, acc0);        // hi*lo
        acc1 = MFMA(ah1, bl, acc1);
        acc0 = MFMA(al0, bh, acc0);        // lo*hi
        acc1 = MFMA(al1, bh, acc1);

        if (c + 2 < NCH) {                 // issue chunk c+2 (stays in flight)
            const int kc = (c + 2) * KC;
            #pragma unroll
            for (int s = 0; s < 4; ++s)
                gll16(sbase[s] + kc, &lds[iw][(wv * 4 + s) * 256]);
        }
        ib = (ib == NBUF - 1) ? 0 : ib + 1;
        iw = (iw == NBUF - 1) ? 0 : iw + 1;
    }

    // ---- K-half reduction: kh==1 writes partials, kh==0 accumulates --------
    __syncthreads();
    float* S = &lds[0][0];                 // 64*65 = 4160 floats < 12288
    if (kh == 1) {
        const int base = (mt * 32 + lo5) * 65;
        #pragma unroll
        for (int r = 0; r < 16; ++r) {
            const int e0 = (r & 3) + 8 * (r >> 2) + 4 * hi5;
            S[base + e0]      = acc0[r];
            S[base + 32 + e0] = acc1[r];
        }
    }
    __syncthreads();
    if (kh == 1) return;
    {
        const int base = (mt * 32 + lo5) * 65;
        #pragma unroll
        for (int r = 0; r < 16; ++r) {
            const int e0 = (r & 3) + 8 * (r >> 2) + 4 * hi5;
            acc0[r] += S[base + e0];
            acc1[r] += S[base + 32 + e0];
        }
    }

    // ---- per-lane top-3 over 32 held experts (e ascending => stable) -------
    float m1 = NEGF, m2 = NEGF, m3 = NEGF;
    int   i1 = 0, i2 = 0;
    #pragma unroll
    for (int r = 0; r < 16; ++r) {
        const float v = acc0[r];
        const int   e = (r & 3) + 8 * (r >> 2) + 4 * hi5;
        if (v > m1)      { m3 = m2; m2 = m1; i2 = i1; m1 = v; i1 = e; }
        else if (v > m2) { m3 = m2; m2 = v; i2 = e; }
        else if (v > m3) { m3 = v; }
    }
    #pragma unroll
    for (int r = 0; r < 16; ++r) {
        const float v = acc1[r];
        const int   e = 32 + (r & 3) + 8 * (r >> 2) + 4 * hi5;
        if (v > m1)      { m3 = m2; m2 = m1; i2 = i1; m1 = v; i1 = e; }
        else if (v > m2) { m3 = m2; m2 = v; i2 = e; }
        else if (v > m3) { m3 = v; }
    }

    // ---- merge sorted triples across lane pair (l, l^32): same token -------
    const float n1 = __shfl_xor(m1, 32), n2 = __shfl_xor(m2, 32), n3 = __shfl_xor(m3, 32);
    const int   j1 = __shfl_xor(i1, 32), j2 = __shfl_xor(i2, 32);

    float a1, a2, a3, b1, b2, b3; int ia1, ia2, ib1, ib2;
    const bool aF = (m1 > n1) || (m1 == n1 && i1 < j1);
    if (aF) { a1=m1; a2=m2; a3=m3; ia1=i1; ia2=i2; b1=n1; b2=n2; b3=n3; ib1=j1; ib2=j2; }
    else    { a1=n1; a2=n2; a3=n3; ia1=j1; ia2=j2; b1=m1; b2=m2; b3=m3; ib1=i1; ib2=i2; }

    const float o1 = a1; const int oi1 = ia1;
    float o2, o3; int oi2;
    const bool a2F = (a2 > b1) || (a2 == b1 && ia2 < ib1);
    if (a2F) { o2 = a2; oi2 = ia2; o3 = (a3 > b1) ? a3 : b1; }
    else     { o2 = b1; oi2 = ib1; o3 = (a2 > b2) ? a2 : b2; }

    if (hi5 == 0) {
        const int t = t0 + mt * 32 + lo5;
        const float r = expf(o2 - o1);       // <= 1
        const float s = 1.0f + r;
        out[2 * t + 0]        = (float)oi1;
        out[2 * t + 1]        = (float)oi2;
        out[woff + 2 * t + 0] = 1.0f / s;
        out[woff + 2 * t + 1] = r / s;
        if ((o1 - o2 < TAU) || (o2 - o3 < TAU)) {
            const int pos = atomicAdd(wl, 1);
            if (pos < wlcap) wl[1 + pos] = t;
        }
    }
}

// ---- Pass 2: fp64 refine, coalesced-W, block per token, 4-wave K-split ----
__global__ __launch_bounds__(256) void moe_refine_fp64(
    const float* __restrict__ x, const float* __restrict__ w,
    float* __restrict__ out, int woff,
    const int* __restrict__ wl, int wlcap)
{
    __shared__ double Sd[3][NE];
    const int lane = threadIdx.x & 63;
    const int wv   = threadIdx.x >> 6;
    const int ks   = wv * 512;                 // this wave's K slice
    int cnt = wl[0];
    if (cnt > wlcap) cnt = wlcap;

    for (int i = blockIdx.x; i < cnt; i += gridDim.x) {
        const int t = wl[1 + i];

        // preload this wave's x slice into fp64 registers (reused by all 64 e)
        const float4 xa = LD4(&x[(size_t)t * H + ks + lane * 4]);
        const float4 xb = LD4(&x[(size_t)t * H + ks + 256 + lane * 4]);
        const double x0 = xa.x, x1 = xa.y, x2 = xa.z, x3 = xa.w;
        const double x4 = xb.x, x5 = xb.y, x6 = xb.z, x7 = xb.w;

        double myacc = 0.0;                    // this lane's expert partial
        #pragma unroll 4
        for (int e = 0; e < NE; ++e) {
            const float4 wa = LD4(&w[(size_t)e * H + ks + lane * 4]);
            const float4 wb = LD4(&w[(size_t)e * H + ks + 256 + lane * 4]);
            double sA = 0.0, sB = 0.0;
            sA = fma((double)wa.x, x0, sA); sA = fma((double)wa.y, x1, sA);
            sA = fma((double)wa.z, x2, sA); sA = fma((double)wa.w, x3, sA);
            sB = fma((double)wb.x, x4, sB); sB = fma((double)wb.y, x5, sB);
            sB = fma((double)wb.z, x6, sB); sB = fma((double)wb.w, x7, sB);
            double s = sA + sB;
            #pragma unroll
            for (int off = 1; off < 64; off <<= 1)
                s += __shfl_xor(s, off);       // all lanes -> identical total
            if (lane == e) myacc = s;
        }

        if (wv > 0) Sd[wv - 1][lane] = myacc;
        __syncthreads();
        if (wv == 0) {
            const double acc = ((myacc + Sd[0][lane]) + Sd[1][lane]) + Sd[2][lane];

            double v = acc; int bi = lane;
            #pragma unroll
            for (int off = 32; off > 0; off >>= 1) {
                double ov = __shfl_xor(v, off);
                int    oi = __shfl_xor(bi, off);
                if (ov > v || (ov == v && oi < bi)) { v = ov; bi = oi; }
            }
            const double m1 = v; const int i1 = bi;

            double v2 = (lane == i1) ? -1.0e300 : acc; int b2 = lane;
            #pragma unroll
            for (int off = 32; off > 0; off >>= 1) {
                double ov = __shfl_xor(v2, off);
                int    oi = __shfl_xor(b2, off);
                if (ov > v2 || (ov == v2 && oi < b2)) { v2 = ov; b2 = oi; }
            }
            const double m2 = v2; const int i2 = b2;

            if (lane == 0) {
                const double r = exp(m2 - m1);
                const double s = 1.0 + r;
                out[2 * t + 0]        = (float)i1;
                out[2 * t + 1]        = (float)i2;
                out[woff + 2 * t + 0] = (float)(1.0 / s);
                out[woff + 2 * t + 1] = (float)(r / s);
            }
        }
        __syncthreads();   // Sd reused next iteration
    }
}

extern "C" void kernel_launch(void* const* d_in, const int* in_sizes, int n_in,
                              void* d_out, int out_size, void* d_ws, size_t ws_size,
                              hipStream_t stream) {
    const float* x   = (const float*)d_in[0];
    const float* wgt = (const float*)d_in[1];
    float* out = (float*)d_out;

    const int T    = in_sizes[0] / H;   // 16384
    const int woff = out_size / 2;      // 32768

    int* wl = (int*)d_ws;
    int wlcap = (int)(ws_size / sizeof(int)) - 1;
    if (wlcap > T) wlcap = T;

    zero_wl<<<dim3(1), dim3(64), 0, stream>>>(wl);

    moe_gate_mfma<<<dim3(T / TOKB), dim3(256), 0, stream>>>(
        x, wgt, out, woff, wl, wlcap);

    moe_refine_fp64<<<dim3(512), dim3(256), 0, stream>>>(
        x, wgt, out, woff, wl, wlcap);
}